// Round 6
// baseline (2100.753 us; speedup 1.0000x reference)
//
#include <hip/hip_runtime.h>

// ---------------- Problem constants ----------------
#define BATCH   2
#define SEQLEN  1024
#define DMODEL  1024
#define DINNER  2048
#define DSTATE  16
#define DCONV   4
#define DTRANK  64
#define GDIM    96              // DTRANK + 2*DSTATE
#define MROWS   (BATCH*SEQLEN)  // 2048

// ---------------- VALU NT GEMM (f32 everywhere) ----------------
// C[m,n] = sum_k A[m,k] * W[n,k];  A: MxK f32 row-major, W: NxK f32 row-major.
// 128x128 tile per 256-thread block, 8x8 accumulators per thread, K-tile = 8.
// M % 128 == 0, K % 8 == 0. N ragged allowed (guarded).
// EPI: 0 = f32 C -> out0
//      1 = f32 softplus(v + bias[n]) -> out0
//      3 = xz split: col < DINNER -> f32 out0 (stride DINNER); else f32 out1 (stride DINNER)
template<int EPI>
__global__ __launch_bounds__(256)
void gemm_valu(const float* __restrict__ A, const float* __restrict__ W,
               float* __restrict__ out0, float* __restrict__ out1,
               const float* __restrict__ bias, int M, int N, int K) {
    __shared__ float As[8][132];   // k-major, padded
    __shared__ float Ws[8][132];

    const int tid  = threadIdx.x;
    const int m0   = blockIdx.x * 128;
    const int n0   = blockIdx.y * 128;
    const int srow = tid >> 1;          // 0..127 staging row
    const int kseg = (tid & 1) * 4;     // 0 or 4
    const int ty   = tid >> 4;          // 0..15  (C row group)
    const int tx   = tid & 15;          // 0..15  (C col group)

    float acc[8][8];
    #pragma unroll
    for (int i = 0; i < 8; i++)
        #pragma unroll
        for (int j = 0; j < 8; j++)
            acc[i][j] = 0.f;

    const float* Ap = A + (size_t)(m0 + srow) * K + kseg;
    const int wrow = n0 + srow;
    const float* Wp = W + (size_t)wrow * K + kseg;
    const bool wv = (wrow < N);

    for (int k0 = 0; k0 < K; k0 += 8) {
        float a4[4], w4[4];
        #pragma unroll
        for (int j = 0; j < 4; j++) a4[j] = Ap[k0 + j];
        #pragma unroll
        for (int j = 0; j < 4; j++) w4[j] = wv ? Wp[k0 + j] : 0.f;

        __syncthreads();   // previous iteration's readers done
        #pragma unroll
        for (int j = 0; j < 4; j++) {
            As[kseg + j][srow] = a4[j];
            Ws[kseg + j][srow] = w4[j];
        }
        __syncthreads();

        #pragma unroll
        for (int kk = 0; kk < 8; kk++) {
            float av[8], wvv[8];
            #pragma unroll
            for (int i = 0; i < 8; i++) av[i] = As[kk][ty * 8 + i];
            #pragma unroll
            for (int j = 0; j < 4; j++) {
                wvv[j]     = Ws[kk][tx * 4 + j];
                wvv[4 + j] = Ws[kk][64 + tx * 4 + j];
            }
            #pragma unroll
            for (int i = 0; i < 8; i++)
                #pragma unroll
                for (int j = 0; j < 8; j++)
                    acc[i][j] += av[i] * wvv[j];
        }
    }

    #pragma unroll
    for (int i = 0; i < 8; i++) {
        int gm = m0 + ty * 8 + i;
        #pragma unroll
        for (int j = 0; j < 8; j++) {
            int gn = n0 + ((j < 4) ? (tx * 4 + j) : (64 + tx * 4 + (j - 4)));
            if (gn < N) {
                float v = acc[i][j];
                if (EPI == 0) {
                    out0[(size_t)gm * N + gn] = v;
                } else if (EPI == 1) {
                    float t = v + bias[gn];
                    out0[(size_t)gm * N + gn] = (t > 20.f) ? t : log1pf(__expf(t));
                } else {
                    if (gn < DINNER)
                        out0[(size_t)gm * DINNER + gn] = v;
                    else
                        out1[(size_t)gm * DINNER + (gn - DINNER)] = v;
                }
            }
        }
    }
}

// ---------------- causal depthwise conv (k=4) + bias + SiLU ----------------
__global__ __launch_bounds__(256)
void conv_silu_kernel(const float* __restrict__ x,
                      const float* __restrict__ cw,
                      const float* __restrict__ cb,
                      float* __restrict__ xc) {
    int idx = blockIdx.x * 256 + threadIdx.x;   // MROWS*DINNER
    int d  = idx & (DINNER - 1);
    int bl = idx >> 11;
    int l  = bl & (SEQLEN - 1);
    float acc = cb[d];
    #pragma unroll
    for (int j = 0; j < DCONV; j++) {
        int lj = l - (DCONV - 1) + j;
        if (lj >= 0)
            acc += cw[d * DCONV + j] * x[(size_t)(bl - (DCONV - 1) + j) * DINNER + d];
    }
    xc[idx] = acc / (1.f + __expf(-acc));   // silu
}

// ---------------- text gate: sigmoid(x_text @ gate_w^T + gate_b) ----------------
__global__ void gate_kernel(const float* __restrict__ x_text,
                            const float* __restrict__ gw,
                            const float* __restrict__ gb,
                            float* __restrict__ gate) {
    int blk = blockIdx.x;        // BATCH*GDIM blocks of 64
    int b = blk / GDIM, j = blk % GDIM;
    int lane = threadIdx.x;
    float s = 0.f;
    for (int k = lane; k < DMODEL; k += 64)
        s += x_text[b * DMODEL + k] * gw[j * DMODEL + k];
    #pragma unroll
    for (int off = 32; off > 0; off >>= 1) s += __shfl_down(s, off);
    if (lane == 0) {
        float t = s + gb[j];
        gate[b * GDIM + j] = 1.f / (1.f + __expf(-t));
    }
}

// ---------------- apply gate; split into dt, B, C (all f32) ----------------
__global__ void gatemul_kernel(const float* __restrict__ xdbl,
                               const float* __restrict__ gate,
                               float* __restrict__ dt,
                               float* __restrict__ Bm,
                               float* __restrict__ Cm) {
    int idx = blockIdx.x * 256 + threadIdx.x;   // MROWS*GDIM
    if (idx >= MROWS * GDIM) return;
    int j  = idx % GDIM;
    int bl = idx / GDIM;
    int b  = bl >> 10;
    float v = xdbl[idx] * gate[b * GDIM + j];
    if (j < DTRANK)               dt[bl * DTRANK + j] = v;
    else if (j < DTRANK + DSTATE) Bm[bl * DSTATE + (j - DTRANK)] = v;
    else                          Cm[bl * DSTATE + (j - DTRANK - DSTATE)] = v;
}

// ---------------- fused sequential selective scan ----------------
// One thread per (b, d); serial over L. y (f32) written in place over xc.
__global__ __launch_bounds__(256)
void scan_fused_kernel(const float* __restrict__ delta,
                       const float* __restrict__ xc,
                       const float* __restrict__ z,
                       const float* __restrict__ Bm,
                       const float* __restrict__ Cm,
                       const float* __restrict__ A_log,
                       const float* __restrict__ Dp,
                       float* __restrict__ y) {
    __shared__ float sB[16][DSTATE];
    __shared__ float sC[16][DSTATE];
    const int tid = threadIdx.x;
    const int d = blockIdx.x * 256 + tid;
    const int b = blockIdx.y;

    float Ac[DSTATE];
    #pragma unroll
    for (int n = 0; n < DSTATE; n++)
        Ac[n] = -__expf(A_log[d * DSTATE + n]);
    const float Dv = Dp[d];
    float h[DSTATE];
    #pragma unroll
    for (int n = 0; n < DSTATE; n++) h[n] = 0.f;

    for (int l0 = 0; l0 < SEQLEN; l0 += 16) {
        __syncthreads();
        {
            int s = tid >> 4, n = tid & 15;   // 256 threads = 16x16
            size_t src = ((size_t)(b * SEQLEN + l0 + s)) * DSTATE + n;
            sB[s][n] = Bm[src];
            sC[s][n] = Cm[src];
        }
        __syncthreads();

        for (int s = 0; s < 16; s++) {
            size_t ix = (size_t)(b * SEQLEN + l0 + s) * DINNER + d;
            float dv = delta[ix];
            float xv = xc[ix];
            float dx = dv * xv;
            float yv = 0.f;
            #pragma unroll
            for (int n = 0; n < DSTATE; n++) {
                float e = __expf(dv * Ac[n]);
                h[n] = h[n] * e + dx * sB[s][n];
                yv += h[n] * sC[s][n];
            }
            float zv = z[ix];
            y[ix] = (yv + Dv * xv) * (zv / (1.f + __expf(-zv)));  // in-place: same thread read-then-write
        }
    }
}

// ---------------- launch ----------------
extern "C" void kernel_launch(void* const* d_in, const int* in_sizes, int n_in,
                              void* d_out, int out_size, void* d_ws, size_t ws_size,
                              hipStream_t stream) {
    const float* hidden   = (const float*)d_in[0];
    const float* x_text   = (const float*)d_in[1];
    const float* in_proj  = (const float*)d_in[2];
    const float* conv_w   = (const float*)d_in[3];
    const float* conv_b   = (const float*)d_in[4];
    const float* x_proj   = (const float*)d_in[5];
    const float* dt_proj  = (const float*)d_in[6];
    const float* dt_bias  = (const float*)d_in[7];
    const float* A_log    = (const float*)d_in[8];
    const float* Dparam   = (const float*)d_in[9];
    const float* out_proj = (const float*)d_in[10];
    const float* gate_w   = (const float*)d_in[11];
    const float* gate_b   = (const float*)d_in[12];

    char* ws = (char*)d_ws;
    size_t off = 0;
    auto alloc = [&](size_t bytes) -> char* {
        char* p = ws + off;
        off += (bytes + 255) & ~(size_t)255;
        return p;
    };
    // ~50 MB total, all f32
    float* xbuf = (float*)alloc((size_t)MROWS * DINNER * 4);  // 16 MB: x; later delta aliases (x dead after conv)
    float* zbuf = (float*)alloc((size_t)MROWS * DINNER * 4);  // 16 MB: z
    float* xc   = (float*)alloc((size_t)MROWS * DINNER * 4);  // 16 MB: xc, later y in place
    float* xdbl = (float*)alloc((size_t)MROWS * GDIM * 4);    // .75 MB
    float* gate = (float*)alloc((size_t)BATCH * GDIM * 4);
    float* dt   = (float*)alloc((size_t)MROWS * DTRANK * 4);  // .5 MB
    float* Bm   = (float*)alloc((size_t)MROWS * DSTATE * 4);
    float* Cm   = (float*)alloc((size_t)MROWS * DSTATE * 4);
    float* delta = xbuf;   // aliases x region

    // 1. in_proj: xz = hidden @ in_proj^T  (2048 x 4096, K=1024) -> x f32 / z f32
    gemm_valu<3><<<dim3(MROWS / 128, (2 * DINNER) / 128), 256, 0, stream>>>(
        hidden, in_proj, xbuf, zbuf, nullptr, MROWS, 2 * DINNER, DMODEL);

    // 2. causal conv + silu -> xc
    conv_silu_kernel<<<(MROWS * DINNER) / 256, 256, 0, stream>>>(
        xbuf, conv_w, conv_b, xc);

    // 3. text gate
    gate_kernel<<<BATCH * GDIM, 64, 0, stream>>>(x_text, gate_w, gate_b, gate);

    // 4. x_proj: x_dbl = xc @ x_proj^T  (2048 x 96, K=2048) -> f32
    gemm_valu<0><<<dim3(MROWS / 128, 1), 256, 0, stream>>>(
        xc, x_proj, xdbl, nullptr, nullptr, MROWS, GDIM, DINNER);

    // 5. gate multiply + split -> dt/Bm/Cm
    gatemul_kernel<<<(MROWS * GDIM + 255) / 256, 256, 0, stream>>>(
        xdbl, gate, dt, Bm, Cm);

    // 6. dt_proj + softplus: delta  (2048 x 2048, K=64) -> f32 (aliases dead x region)
    gemm_valu<1><<<dim3(MROWS / 128, DINNER / 128), 256, 0, stream>>>(
        dt, dt_proj, delta, nullptr, dt_bias, MROWS, DINNER, DTRANK);

    // 7. fused sequential scan -> y f32 (in place over xc)
    scan_fused_kernel<<<dim3(DINNER / 256, BATCH), 256, 0, stream>>>(
        delta, xc, zbuf, Bm, Cm, A_log, Dparam, xc);

    // 8. out_proj -> d_out f32  (2048 x 1024, K=2048)
    gemm_valu<0><<<dim3(MROWS / 128, DMODEL / 128), 256, 0, stream>>>(
        xc, out_proj, (float*)d_out, nullptr, nullptr, MROWS, DMODEL, DINNER);
}

// Round 7
// 412.574 us; speedup vs baseline: 5.0918x; 5.0918x over previous
//
#include <hip/hip_runtime.h>

// ---------------- Problem constants ----------------
#define BATCH   2
#define SEQLEN  1024
#define DMODEL  1024
#define DINNER  2048
#define DSTATE  16
#define DCONV   4
#define DTRANK  64
#define GDIM    96              // DTRANK + 2*DSTATE
#define MROWS   (BATCH*SEQLEN)  // 2048

#define NCHUNK  32              // chunks over L
#define LCHUNK  32              // SEQLEN / NCHUNK

typedef __attribute__((ext_vector_type(8))) short bf16x8_t;
typedef __attribute__((ext_vector_type(4))) float f32x4_t;

// bf16 <-> f32 helpers (round-to-nearest-even)
__device__ __forceinline__ unsigned short f2bf(float x) {
    union { float f; unsigned int u; } v; v.f = x;
    unsigned int r = v.u + 0x7FFFu + ((v.u >> 16) & 1u);
    return (unsigned short)(r >> 16);
}
__device__ __forceinline__ float bf2f(unsigned short h) {
    union { unsigned int u; float f; } v; v.u = ((unsigned int)h) << 16;
    return v.f;
}

// split 8 f32 into hi/lo bf16 octets
__device__ __forceinline__ void split8(const float* x, bf16x8_t& hi, bf16x8_t& lo) {
    #pragma unroll
    for (int j = 0; j < 8; j++) {
        unsigned short h = f2bf(x[j]);
        float r = x[j] - bf2f(h);
        hi[j] = (short)h;
        lo[j] = (short)f2bf(r);
    }
}

// ---------------- Split-precision NT MFMA GEMM ----------------
// C[m,n] = sum_k A[m,k]*W[n,k]; A: MxK f32 row-major, W: NxK f32 row-major.
// M%64==0, K%32==0. N ragged allowed. Each operand split hi+lo bf16; 3 MFMAs
// (hi*hi + hi*lo + lo*hi) -> ~2^-18 relative error.  f32 outputs.
// Cross-validated vs the VALU GEMM (rounds 3/4: identical results).
// EPI: 0 = f32 C -> out0
//      1 = f32 softplus(v + bias[n]) -> out0
//      3 = xz split: col < DINNER -> out0 (stride DINNER); else out1 (stride DINNER)
template<int EPI>
__global__ __launch_bounds__(256)
void gemm_nt(const float* __restrict__ A,
             const float* __restrict__ W,
             float* __restrict__ out0,
             float* __restrict__ out1,
             const float* __restrict__ bias,
             int M, int N, int K) {
    __shared__ __align__(16) short As[2][64][40];  // [hi/lo][row][k], pad 32->40
    __shared__ __align__(16) short Bs[2][64][40];

    const int tid  = threadIdx.x;
    const int m0   = blockIdx.x * 64;
    const int n0   = blockIdx.y * 64;
    const int row  = tid >> 2;          // 0..63 staging row
    const int kc   = (tid & 3) * 8;     // 0,8,16,24 staging k-offset (elements)
    const int w    = tid >> 6;          // wave 0..3
    const int lane = tid & 63;
    const int quad = lane >> 4;
    const int l15  = lane & 15;
    const int wm   = (w >> 1) * 32;
    const int wn   = (w & 1) * 32;

    f32x4_t acc[2][2];
    #pragma unroll
    for (int i = 0; i < 2; i++)
        #pragma unroll
        for (int j = 0; j < 2; j++)
            acc[i][j] = (f32x4_t){0.f, 0.f, 0.f, 0.f};

    const float* Ap = A + (size_t)(m0 + row) * K + kc;
    const int brow = n0 + row;
    const float* Wp = W + (size_t)brow * K + kc;
    const bool wvalid = (brow < N);

    for (int k0 = 0; k0 < K; k0 += 32) {
        float ax[8];
        *(float4*)(ax)     = *(const float4*)(Ap + k0);
        *(float4*)(ax + 4) = *(const float4*)(Ap + k0 + 4);
        bf16x8_t ah, al;
        split8(ax, ah, al);

        float wx[8] = {0,0,0,0,0,0,0,0};
        if (wvalid) {
            *(float4*)(wx)     = *(const float4*)(Wp + k0);
            *(float4*)(wx + 4) = *(const float4*)(Wp + k0 + 4);
        }
        bf16x8_t bh, bl;
        split8(wx, bh, bl);

        __syncthreads();   // previous iteration's readers done
        *(bf16x8_t*)(&As[0][row][kc]) = ah;
        *(bf16x8_t*)(&As[1][row][kc]) = al;
        *(bf16x8_t*)(&Bs[0][row][kc]) = bh;
        *(bf16x8_t*)(&Bs[1][row][kc]) = bl;
        __syncthreads();

        bf16x8_t a0h = *(const bf16x8_t*)(&As[0][wm +  0 + l15][quad * 8]);
        bf16x8_t a1h = *(const bf16x8_t*)(&As[0][wm + 16 + l15][quad * 8]);
        bf16x8_t a0l = *(const bf16x8_t*)(&As[1][wm +  0 + l15][quad * 8]);
        bf16x8_t a1l = *(const bf16x8_t*)(&As[1][wm + 16 + l15][quad * 8]);
        bf16x8_t b0h = *(const bf16x8_t*)(&Bs[0][wn +  0 + l15][quad * 8]);
        bf16x8_t b1h = *(const bf16x8_t*)(&Bs[0][wn + 16 + l15][quad * 8]);
        bf16x8_t b0l = *(const bf16x8_t*)(&Bs[1][wn +  0 + l15][quad * 8]);
        bf16x8_t b1l = *(const bf16x8_t*)(&Bs[1][wn + 16 + l15][quad * 8]);

        acc[0][0] = __builtin_amdgcn_mfma_f32_16x16x32_bf16(a0h, b0h, acc[0][0], 0, 0, 0);
        acc[0][0] = __builtin_amdgcn_mfma_f32_16x16x32_bf16(a0h, b0l, acc[0][0], 0, 0, 0);
        acc[0][0] = __builtin_amdgcn_mfma_f32_16x16x32_bf16(a0l, b0h, acc[0][0], 0, 0, 0);

        acc[0][1] = __builtin_amdgcn_mfma_f32_16x16x32_bf16(a0h, b1h, acc[0][1], 0, 0, 0);
        acc[0][1] = __builtin_amdgcn_mfma_f32_16x16x32_bf16(a0h, b1l, acc[0][1], 0, 0, 0);
        acc[0][1] = __builtin_amdgcn_mfma_f32_16x16x32_bf16(a0l, b1h, acc[0][1], 0, 0, 0);

        acc[1][0] = __builtin_amdgcn_mfma_f32_16x16x32_bf16(a1h, b0h, acc[1][0], 0, 0, 0);
        acc[1][0] = __builtin_amdgcn_mfma_f32_16x16x32_bf16(a1h, b0l, acc[1][0], 0, 0, 0);
        acc[1][0] = __builtin_amdgcn_mfma_f32_16x16x32_bf16(a1l, b0h, acc[1][0], 0, 0, 0);

        acc[1][1] = __builtin_amdgcn_mfma_f32_16x16x32_bf16(a1h, b1h, acc[1][1], 0, 0, 0);
        acc[1][1] = __builtin_amdgcn_mfma_f32_16x16x32_bf16(a1h, b1l, acc[1][1], 0, 0, 0);
        acc[1][1] = __builtin_amdgcn_mfma_f32_16x16x32_bf16(a1l, b1h, acc[1][1], 0, 0, 0);
    }

    #pragma unroll
    for (int mi = 0; mi < 2; mi++) {
        #pragma unroll
        for (int ni = 0; ni < 2; ni++) {
            #pragma unroll
            for (int r = 0; r < 4; r++) {
                int gm = m0 + wm + mi * 16 + quad * 4 + r;
                int gn = n0 + wn + ni * 16 + l15;
                if (gn < N) {
                    float v = acc[mi][ni][r];
                    if (EPI == 0) {
                        out0[(size_t)gm * N + gn] = v;
                    } else if (EPI == 1) {
                        float t = v + bias[gn];
                        out0[(size_t)gm * N + gn] = (t > 20.f) ? t : log1pf(__expf(t));
                    } else {
                        if (gn < DINNER)
                            out0[(size_t)gm * DINNER + gn] = v;
                        else
                            out1[(size_t)gm * DINNER + (gn - DINNER)] = v;
                    }
                }
            }
        }
    }
}

// ---------------- causal depthwise conv (k=4) + bias + SiLU ----------------
__global__ __launch_bounds__(256)
void conv_silu_kernel(const float* __restrict__ x,
                      const float* __restrict__ cw,
                      const float* __restrict__ cb,
                      float* __restrict__ xc) {
    int idx = blockIdx.x * 256 + threadIdx.x;   // MROWS*DINNER
    int d  = idx & (DINNER - 1);
    int bl = idx >> 11;
    int l  = bl & (SEQLEN - 1);
    float acc = cb[d];
    #pragma unroll
    for (int j = 0; j < DCONV; j++) {
        int lj = l - (DCONV - 1) + j;
        if (lj >= 0)
            acc += cw[d * DCONV + j] * x[(size_t)(bl - (DCONV - 1) + j) * DINNER + d];
    }
    xc[idx] = acc / (1.f + __expf(-acc));   // silu
}

// ---------------- text gate: sigmoid(x_text @ gate_w^T + gate_b) ----------------
__global__ void gate_kernel(const float* __restrict__ x_text,
                            const float* __restrict__ gw,
                            const float* __restrict__ gb,
                            float* __restrict__ gate) {
    int blk = blockIdx.x;        // BATCH*GDIM blocks of 64
    int b = blk / GDIM, j = blk % GDIM;
    int lane = threadIdx.x;
    float s = 0.f;
    for (int k = lane; k < DMODEL; k += 64)
        s += x_text[b * DMODEL + k] * gw[j * DMODEL + k];
    #pragma unroll
    for (int off = 32; off > 0; off >>= 1) s += __shfl_down(s, off);
    if (lane == 0) {
        float t = s + gb[j];
        gate[b * GDIM + j] = 1.f / (1.f + __expf(-t));
    }
}

// ---------------- apply gate; split into dt, B, C (all f32) ----------------
__global__ void gatemul_kernel(const float* __restrict__ xdbl,
                               const float* __restrict__ gate,
                               float* __restrict__ dt,
                               float* __restrict__ Bm,
                               float* __restrict__ Cm) {
    int idx = blockIdx.x * 256 + threadIdx.x;   // MROWS*GDIM
    if (idx >= MROWS * GDIM) return;
    int j  = idx % GDIM;
    int bl = idx / GDIM;
    int b  = bl >> 10;
    float v = xdbl[idx] * gate[b * GDIM + j];
    if (j < DTRANK)               dt[bl * DTRANK + j] = v;
    else if (j < DTRANK + DSTATE) Bm[bl * DSTATE + (j - DTRANK)] = v;
    else                          Cm[bl * DSTATE + (j - DTRANK - DSTATE)] = v;
}

// ---------------- scan pass 1: per-chunk local h and dA-product ----------------
__global__ __launch_bounds__(256)
void scan1_kernel(const float* __restrict__ delta,
                  const float* __restrict__ xc,
                  const float* __restrict__ Bm,
                  const float* __restrict__ A_log,
                  float* __restrict__ hfin,
                  float* __restrict__ aprod) {
    __shared__ float sBm[LCHUNK][DSTATE];
    int tid = threadIdx.x;
    int d = blockIdx.x * 256 + tid;
    int b = blockIdx.y;
    int c = blockIdx.z;
    int l0 = c * LCHUNK;
    for (int t = tid; t < LCHUNK * DSTATE; t += 256)
        sBm[t >> 4][t & 15] = Bm[((size_t)(b * SEQLEN + l0 + (t >> 4))) * DSTATE + (t & 15)];
    __syncthreads();

    float Ac[DSTATE];
    #pragma unroll
    for (int n = 0; n < DSTATE; n++)
        Ac[n] = -__expf(A_log[d * DSTATE + n]);
    float h[DSTATE], p[DSTATE];
    #pragma unroll
    for (int n = 0; n < DSTATE; n++) { h[n] = 0.f; p[n] = 1.f; }

    for (int s = 0; s < LCHUNK; s++) {
        size_t ix = (size_t)(b * SEQLEN + l0 + s) * DINNER + d;
        float dv = delta[ix];
        float xv = xc[ix];
        float dx = dv * xv;
        #pragma unroll
        for (int n = 0; n < DSTATE; n++) {
            float e = __expf(dv * Ac[n]);
            h[n] = h[n] * e + dx * sBm[s][n];
            p[n] *= e;
        }
    }
    size_t base = ((size_t)(b * DINNER + d) * NCHUNK + c) * DSTATE;
    #pragma unroll
    for (int n = 0; n < DSTATE; n++) { hfin[base + n] = h[n]; aprod[base + n] = p[n]; }
}

// ---------------- scan pass 2: chunk-level prefix (h_start in place) ----------------
__global__ void scan2_kernel(float* __restrict__ hfin,
                             const float* __restrict__ aprod) {
    int idx = blockIdx.x * 256 + threadIdx.x;   // BATCH*DINNER*DSTATE
    int n  = idx & 15;
    int bd = idx >> 4;
    size_t base = (size_t)bd * NCHUNK * DSTATE + n;
    float hs = 0.f;
    for (int c = 0; c < NCHUNK; c++) {
        size_t o = base + (size_t)c * DSTATE;
        float hf = hfin[o];
        float ap = aprod[o];
        hfin[o] = hs;            // h_start for chunk c
        hs = hf + ap * hs;
    }
}

// ---------------- scan pass 3: replay with h0, emit y = (scan + D*xc)*silu(z) ----------------
// yout aliases xc (in-place): each (b,l,d) element owned by one thread, read-then-write.
__global__ __launch_bounds__(256)
void scan3_kernel(const float* __restrict__ delta,
                  const float* __restrict__ xc,
                  const float* __restrict__ z,
                  const float* __restrict__ Bm,
                  const float* __restrict__ Cm,
                  const float* __restrict__ A_log,
                  const float* __restrict__ Dp,
                  const float* __restrict__ hstart,
                  float* __restrict__ yout) {
    __shared__ float sBm[LCHUNK][DSTATE];
    __shared__ float sCm[LCHUNK][DSTATE];
    int tid = threadIdx.x;
    int d = blockIdx.x * 256 + tid;
    int b = blockIdx.y;
    int c = blockIdx.z;
    int l0 = c * LCHUNK;
    for (int t = tid; t < LCHUNK * DSTATE; t += 256) {
        size_t src = ((size_t)(b * SEQLEN + l0 + (t >> 4))) * DSTATE + (t & 15);
        sBm[t >> 4][t & 15] = Bm[src];
        sCm[t >> 4][t & 15] = Cm[src];
    }
    __syncthreads();

    float Ac[DSTATE];
    #pragma unroll
    for (int n = 0; n < DSTATE; n++)
        Ac[n] = -__expf(A_log[d * DSTATE + n]);
    float h[DSTATE];
    size_t base = ((size_t)(b * DINNER + d) * NCHUNK + c) * DSTATE;
    #pragma unroll
    for (int n = 0; n < DSTATE; n++) h[n] = hstart[base + n];
    float Dv = Dp[d];

    for (int s = 0; s < LCHUNK; s++) {
        size_t ix = (size_t)(b * SEQLEN + l0 + s) * DINNER + d;
        float dv = delta[ix];
        float xv = xc[ix];
        float dx = dv * xv;
        float y = 0.f;
        #pragma unroll
        for (int n = 0; n < DSTATE; n++) {
            float e = __expf(dv * Ac[n]);
            h[n] = h[n] * e + dx * sBm[s][n];
            y += h[n] * sCm[s][n];
        }
        float zv = z[ix];
        yout[ix] = (y + Dv * xv) * (zv / (1.f + __expf(-zv)));
    }
}

// ---------------- launch ----------------
extern "C" void kernel_launch(void* const* d_in, const int* in_sizes, int n_in,
                              void* d_out, int out_size, void* d_ws, size_t ws_size,
                              hipStream_t stream) {
    const float* hidden   = (const float*)d_in[0];
    const float* x_text   = (const float*)d_in[1];
    const float* in_proj  = (const float*)d_in[2];
    const float* conv_w   = (const float*)d_in[3];
    const float* conv_b   = (const float*)d_in[4];
    const float* x_proj   = (const float*)d_in[5];
    const float* dt_proj  = (const float*)d_in[6];
    const float* dt_bias  = (const float*)d_in[7];
    const float* A_log    = (const float*)d_in[8];
    const float* Dparam   = (const float*)d_in[9];
    const float* out_proj = (const float*)d_in[10];
    const float* gate_w   = (const float*)d_in[11];
    const float* gate_b   = (const float*)d_in[12];

    char* ws = (char*)d_ws;
    size_t off = 0;
    auto alloc = [&](size_t bytes) -> char* {
        char* p = ws + off;
        off += (bytes + 255) & ~(size_t)255;
        return p;
    };
    // ~66.5 MB total, all f32
    float* xbuf  = (float*)alloc((size_t)MROWS * DINNER * 4);  // 16 MB: x; later delta aliases
    float* zbuf  = (float*)alloc((size_t)MROWS * DINNER * 4);  // 16 MB: z
    float* xc    = (float*)alloc((size_t)MROWS * DINNER * 4);  // 16 MB: xc, later y in place
    float* xdbl  = (float*)alloc((size_t)MROWS * GDIM * 4);    // .75 MB
    float* gate  = (float*)alloc((size_t)BATCH * GDIM * 4);
    float* dt    = (float*)alloc((size_t)MROWS * DTRANK * 4);  // .5 MB
    float* Bm    = (float*)alloc((size_t)MROWS * DSTATE * 4);
    float* Cm    = (float*)alloc((size_t)MROWS * DSTATE * 4);
    float* hfin  = (float*)alloc((size_t)BATCH * DINNER * NCHUNK * DSTATE * 4); // 8.4 MB
    float* aprod = (float*)alloc((size_t)BATCH * DINNER * NCHUNK * DSTATE * 4); // 8.4 MB
    float* delta = xbuf;   // aliases x region (x dead after conv)

    // 1. in_proj: xz = hidden @ in_proj^T  (2048 x 4096, K=1024) -> x / z
    gemm_nt<3><<<dim3(MROWS / 64, (2 * DINNER) / 64), 256, 0, stream>>>(
        hidden, in_proj, xbuf, zbuf, nullptr, MROWS, 2 * DINNER, DMODEL);

    // 2. causal conv + silu -> xc
    conv_silu_kernel<<<(MROWS * DINNER) / 256, 256, 0, stream>>>(
        xbuf, conv_w, conv_b, xc);

    // 3. text gate
    gate_kernel<<<BATCH * GDIM, 64, 0, stream>>>(x_text, gate_w, gate_b, gate);

    // 4. x_proj: x_dbl = xc @ x_proj^T  (2048 x 96, K=2048)
    gemm_nt<0><<<dim3(MROWS / 64, 2), 256, 0, stream>>>(
        xc, x_proj, xdbl, nullptr, nullptr, MROWS, GDIM, DINNER);

    // 5. gate multiply + split -> dt/Bm/Cm
    gatemul_kernel<<<(MROWS * GDIM + 255) / 256, 256, 0, stream>>>(
        xdbl, gate, dt, Bm, Cm);

    // 6. dt_proj + softplus: delta  (2048 x 2048, K=64) -> aliases dead x region
    gemm_nt<1><<<dim3(MROWS / 64, DINNER / 64), 256, 0, stream>>>(
        dt, dt_proj, delta, nullptr, dt_bias, MROWS, DINNER, DTRANK);

    // 7-9. chunked parallel scan (512 blocks per elem-pass vs 16 for fused)
    scan1_kernel<<<dim3(DINNER / 256, BATCH, NCHUNK), 256, 0, stream>>>(
        delta, xc, Bm, A_log, hfin, aprod);
    scan2_kernel<<<(BATCH * DINNER * DSTATE) / 256, 256, 0, stream>>>(
        hfin, aprod);
    scan3_kernel<<<dim3(DINNER / 256, BATCH, NCHUNK), 256, 0, stream>>>(
        delta, xc, zbuf, Bm, Cm, A_log, Dparam, hfin, xc);

    // 10. out_proj -> d_out f32  (2048 x 1024, K=2048)
    gemm_nt<0><<<dim3(MROWS / 64, DMODEL / 64), 256, 0, stream>>>(
        xc, out_proj, (float*)d_out, nullptr, nullptr, MROWS, DMODEL, DINNER);
}